// Round 13
// baseline (3122.568 us; speedup 1.0000x reference)
//
#include <hip/hip_runtime.h>

#define S_ 512
#define B_ 64
#define I_ 1024
#define H_ 1024
#define G_ 4096   // 4*H
#define ROWB 2080 // LDS row stride bytes: 130*16 -> conflict-free frag reads (verified R6)

typedef _Float16 f16x4 __attribute__((ext_vector_type(4)));
typedef _Float16 f16x8 __attribute__((ext_vector_type(8)));
typedef float f32x4 __attribute__((ext_vector_type(4)));

// ---------------- f32 -> f16 (plain) ----------------
__global__ __launch_bounds__(256) void cvt_f32_f16(const float* __restrict__ src,
                                                   _Float16* __restrict__ dst, int n) {
  const int stride = gridDim.x * blockDim.x * 4;
  for (long i = (long)(blockIdx.x * blockDim.x + threadIdx.x) * 4; i < n; i += stride) {
    const float4 v = *(const float4*)(src + i);
    f16x4 o;
    o.x = (_Float16)v.x;
    o.y = (_Float16)v.y;
    o.z = (_Float16)v.z;
    o.w = (_Float16)v.w;
    *(f16x4*)(dst + i) = o;
  }
}

// ---------------- async global->LDS helper (16B per lane) ----------------
__device__ __forceinline__ void gload16(const void* g, void* l) {
  __builtin_amdgcn_global_load_lds(
      (const __attribute__((address_space(1))) unsigned int*)g,
      (__attribute__((address_space(3))) unsigned int*)l, 16, 0, 0);
}

// ---------------- coherent (bypass L1/L2, served by MALL) access helpers ----------------
__device__ __forceinline__ uint4 ld_coh_x4(const unsigned int* p) {
  uint4 v;
  asm volatile("global_load_dwordx4 %0, %1, off sc0 sc1" : "=v"(v) : "v"(p) : "memory");
  return v;
}
__device__ __forceinline__ unsigned ld_coh_wait(const unsigned int* p) {
  unsigned v;
  asm volatile("global_load_dword %0, %1, off sc0 sc1\n\ts_waitcnt vmcnt(0)"
               : "=v"(v) : "v"(p) : "memory");
  return v;
}
__device__ __forceinline__ void st_coh(unsigned int* p, unsigned int v) {
  asm volatile("global_store_dword %0, %1, off sc0 sc1" : : "v"(p), "v"(v) : "memory");
}
__device__ __forceinline__ void st_coh16(unsigned short* p, unsigned int v) {
  asm volatile("global_store_short %0, %1, off sc0 sc1" : : "v"(p), "v"(v) : "memory");
}
__device__ __forceinline__ void wait_vm0() {
  asm volatile("s_waitcnt vmcnt(0)" ::: "memory");
}
__device__ __forceinline__ f16x8 ld_g_f16x8(const _Float16* p) {
  f16x8 v;
  asm volatile("global_load_dwordx4 %0, %1, off" : "=v"(v) : "v"(p) : "memory");
  return v;
}

// ---------------- x_gates GEMM: C = f16(x[f32]) * f16(Wx)^T + (bx+bh), f16 out ----------------
// A consumed as f32 directly (cvt_x pass fused away): A staged f32 via
// global_load_lds (R2-verified layout), fragments converted in-register.
// 128x128 tile, BK=32, 4 waves (2x2 of 64x64).
__global__ __launch_bounds__(256) void gemm_xg(const float* __restrict__ A,
                                               const _Float16* __restrict__ Bm,
                                               const float* __restrict__ bx,
                                               const float* __restrict__ bh,
                                               _Float16* __restrict__ C) {
  __shared__ __align__(16) float As[128 * 32];       // 16 KB
  __shared__ __align__(16) _Float16 Bs[128 * 32];    // 8 KB
  const int tileN = (blockIdx.x & 31) << 7;
  const int tileM = (blockIdx.x >> 5) << 7;
  const int w = threadIdx.x >> 6;
  const int lane = threadIdx.x & 63;
  const int wm = w & 1, wn = w >> 1;

  // A staging: 16 chunks of 8 rows x 32 f32 (1KB); wave w does chunks 4w..4w+3
  const int arow = lane >> 3;         // 0..7
  const int acol = (lane & 7) << 2;   // f32 col (4 floats = 16B)
  const float* ap0 = A + (long)(tileM + (4 * w + 0) * 8 + arow) * I_ + acol;
  const float* ap1 = A + (long)(tileM + (4 * w + 1) * 8 + arow) * I_ + acol;
  const float* ap2 = A + (long)(tileM + (4 * w + 2) * 8 + arow) * I_ + acol;
  const float* ap3 = A + (long)(tileM + (4 * w + 3) * 8 + arow) * I_ + acol;
  // B staging: 8 chunks of 16 rows x 32 f16 (1KB); wave w does chunks 2w, 2w+1
  const int brow = lane >> 2;         // 0..15
  const int bcol = (lane & 3) << 3;   // f16 col (8 halves = 16B)
  const _Float16* pB0 = Bm + (long)(tileN + (2 * w + 0) * 16 + brow) * I_ + bcol;
  const _Float16* pB1 = Bm + (long)(tileN + (2 * w + 1) * 16 + brow) * I_ + bcol;

  f32x4 acc[4][4] = {};
  const int fr = lane & 15;
  const int fk = (lane >> 4) << 3;

  for (int kk = 0; kk < I_; kk += 32) {
    gload16(ap0 + kk, &As[(4 * w + 0) * 256]);
    gload16(ap1 + kk, &As[(4 * w + 1) * 256]);
    gload16(ap2 + kk, &As[(4 * w + 2) * 256]);
    gload16(ap3 + kk, &As[(4 * w + 3) * 256]);
    gload16(pB0 + kk, &Bs[(2 * w + 0) * 512]);
    gload16(pB1 + kk, &Bs[(2 * w + 1) * 512]);
    __syncthreads();
    f16x8 af[4], bf[4];
#pragma unroll
    for (int i = 0; i < 4; ++i) {
      const float* ap = &As[(wm * 64 + i * 16 + fr) * 32 + fk];
      const float4 v0 = *(const float4*)ap;
      const float4 v1 = *(const float4*)(ap + 4);
      float vv[8] = {v0.x, v0.y, v0.z, v0.w, v1.x, v1.y, v1.z, v1.w};
#pragma unroll
      for (int j = 0; j < 8; ++j) af[i][j] = (_Float16)vv[j];
      bf[i] = *(const f16x8*)&Bs[(wn * 64 + i * 16 + fr) * 32 + fk];
    }
#pragma unroll
    for (int i = 0; i < 4; ++i)
#pragma unroll
      for (int j = 0; j < 4; ++j)
        acc[i][j] = __builtin_amdgcn_mfma_f32_16x16x32_f16(af[i], bf[j], acc[i][j], 0, 0, 0);
    __syncthreads();
  }

#pragma unroll
  for (int j = 0; j < 4; ++j) {
    const int col = tileN + wn * 64 + j * 16 + fr;
    const float bias = bx[col] + bh[col];
#pragma unroll
    for (int i = 0; i < 4; ++i) {
      const int row0 = tileM + wm * 64 + i * 16 + ((lane >> 4) << 2);
#pragma unroll
      for (int r = 0; r < 4; ++r)
        C[(long)(row0 + r) * G_ + col] = (_Float16)(acc[i][j][r] + bias);
    }
  }
}

// ---------------- flag reset (every launch, stream-ordered) ----------------
__global__ void zero_counters(unsigned int* c, int n) {
  for (int i = threadIdx.x; i < n; i += blockDim.x) c[i] = 0;
}

// ---------------- persistent LSTM scan (R8/R11-verified structure, verbatim) ----------------
// 256 WGs x 256 threads (4 waves), 1 WG/CU. WG=(bg,hs); wave w = gate w.
// Wh pinned in 128 regs/lane (asm loads). h published as ONE f16 plane via
// MALL-coherent stores; reader stages 32KB -> LDS; 32 MFMAs/wave/step.
// Per-WAVE flags; poll wave-split (wave w watches its 16 WGs' 4 flags).
__global__ __launch_bounds__(256, 1) void lstm_scan(
    const _Float16* __restrict__ xg, const _Float16* __restrict__ Whh,
    unsigned short* __restrict__ hH0, unsigned short* __restrict__ hH1,
    float* __restrict__ out, float* __restrict__ hT, float* __restrict__ cT,
    unsigned int* __restrict__ flags) {
  __shared__ __align__(16) char hhS[16 * ROWB];  // 33.3 KB
  __shared__ float gbuf[4][16][16];              // 4 KB
  const int bg = blockIdx.x >> 6;
  const int hs = blockIdx.x & 63;
  const int tid = threadIdx.x;
  const int w = tid >> 6;
  const int lane = tid & 63;
  const int fr = lane & 15;
  const int fkg = lane >> 4;  // 0..3

  // ---- Wh -> regs, once, via asm loads (non-rematerializable) ----
  f16x8 wreg[32];
  {
    const _Float16* wrow = Whh + (long)(w * H_ + hs * 16 + fr) * H_ + fkg * 8;
#pragma unroll
    for (int it = 0; it < 32; ++it) wreg[it] = ld_g_f16x8(wrow + it * 32);
    wait_vm0();
    __builtin_amdgcn_sched_barrier(0);
  }

  const int b = tid >> 4, j = tid & 15;
  const int gb = bg * 16 + b;
  const int gj = hs * 16 + j;
  float c = 0.f;

  // staging source (u32 units): plane f16[64][1024]; this bg's block = 8192 u32
  const unsigned int* sH0 = (const unsigned int*)hH0 + bg * 8192 + tid * 4;
  const unsigned int* sH1 = (const unsigned int*)hH1 + bg * 8192 + tid * 4;
  // LDS dest: chunk ci = i*256+tid -> row = 2i + (tid>>7), col16 = tid&127
  const int lds0 = (tid >> 7) * ROWB + (tid & 127) * 16;
  // fragment read base: row fr, k-group fkg
  const char* hhrow = hhS + fr * ROWB + fkg * 16;
  // poll: wave w watches WGs bg*64 + w*16 + (lane>>2), flag (lane&3)
  const unsigned int* pollp = flags + (bg * 64 + w * 16 + (lane >> 2)) * 4 + (lane & 3);
  unsigned int* myflag = flags + blockIdx.x * 4 + w;

  // xg prefetch for t=0
  float gi = (float)xg[(long)gb * G_ + gj];
  float gf = (float)xg[(long)gb * G_ + gj + H_];
  float gg = (float)xg[(long)gb * G_ + gj + 2 * H_];
  float go = (float)xg[(long)gb * G_ + gj + 3 * H_];

  for (int t = 0; t < S_; ++t) {
    if (t > 0) {
      // ---- wait for h(t-1): all 64 WGs x 4 waves of this batch-group ----
      const unsigned tgt = (unsigned)t;
      while (!__all(ld_coh_wait(pollp) >= tgt)) __builtin_amdgcn_s_sleep(1);
      __syncthreads();

      // ---- stage h(t-1) plane -> LDS (32KB, 8 dwordx4/thread) ----
      const unsigned int* sH = (t & 1) ? sH0 : sH1;
      uint4 qh[8];
#pragma unroll
      for (int i = 0; i < 8; ++i) qh[i] = ld_coh_x4(sH + i * 1024);
      wait_vm0();
      __builtin_amdgcn_sched_barrier(0);
#pragma unroll
      for (int i = 0; i < 8; ++i)
        *(uint4*)(hhS + lds0 + i * (2 * ROWB)) = qh[i];
      __syncthreads();

      // ---- gates = h @ Wh^T ; 4 independent MFMA chains of 8 ----
      f32x4 a0 = {}, a1 = {}, a2 = {}, a3 = {};
#pragma unroll
      for (int it = 0; it < 32; it += 4) {
        a0 = __builtin_amdgcn_mfma_f32_16x16x32_f16(*(const f16x8*)(hhrow + it * 64), wreg[it], a0, 0, 0, 0);
        a1 = __builtin_amdgcn_mfma_f32_16x16x32_f16(*(const f16x8*)(hhrow + (it + 1) * 64), wreg[it + 1], a1, 0, 0, 0);
        a2 = __builtin_amdgcn_mfma_f32_16x16x32_f16(*(const f16x8*)(hhrow + (it + 2) * 64), wreg[it + 2], a2, 0, 0, 0);
        a3 = __builtin_amdgcn_mfma_f32_16x16x32_f16(*(const f16x8*)(hhrow + (it + 3) * 64), wreg[it + 3], a3, 0, 0, 0);
      }
#pragma unroll
      for (int r = 0; r < 4; ++r)
        gbuf[w][fkg * 4 + r][fr] = (a0[r] + a1[r]) + (a2[r] + a3[r]);
      __syncthreads();
      gi += gbuf[0][b][j];
      gf += gbuf[1][b][j];
      gg += gbuf[2][b][j];
      go += gbuf[3][b][j];
    }

    const float iv = 1.f / (1.f + __expf(-gi));
    const float fv = 1.f / (1.f + __expf(-gf));
    const float gv = tanhf(gg);
    const float ov = 1.f / (1.f + __expf(-go));
    c = fv * c + iv * gv;
    const float hn = ov * tanhf(c);

    if (t + 1 < S_) {
      // ---- publish h(t) to parity plane, wave-drain, wave flag ----
      unsigned short* pH = ((t & 1) ? hH1 : hH0) + gb * 1024 + gj;
      st_coh16(pH, (unsigned)__builtin_bit_cast(unsigned short, (_Float16)hn));
      wait_vm0();  // this wave's h store visible at the coherent point
      if (lane == 0) st_coh(myflag, (unsigned)(t + 1));
      // off-critical-path work after the flag
      out[((long)gb * S_ + t) * H_ + gj] = hn;
      const _Float16* xq = xg + ((long)(t + 1) * B_ + gb) * G_ + gj;
      gi = (float)xq[0];
      gf = (float)xq[H_];
      gg = (float)xq[2 * H_];
      go = (float)xq[3 * H_];
    } else {
      out[((long)gb * S_ + t) * H_ + gj] = hn;
      hT[gb * H_ + gj] = hn;
      cT[gb * H_ + gj] = c;
    }
  }
}

// ---------------- launch ----------------
extern "C" void kernel_launch(void* const* d_in, const int* in_sizes, int n_in,
                              void* d_out, int out_size, void* d_ws, size_t ws_size,
                              hipStream_t stream) {
  const float* x = (const float*)d_in[0];
  const float* Wx = (const float*)d_in[1];
  const float* bx = (const float*)d_in[2];
  const float* Wh = (const float*)d_in[3];
  const float* bh = (const float*)d_in[4];

  float* out = (float*)d_out;            // [64][512][1024]
  float* hT = out + (long)B_ * S_ * H_;  // [64][1024]
  float* cT = hT + (long)B_ * H_;        // [64][1024]

  char* ws = (char*)d_ws;
  _Float16* Wx16 = (_Float16*)ws;                  // 8 MB
  _Float16* Whh = (_Float16*)(ws + (8l << 20));    // 8 MB
  char* st = ws + (80l << 20);
  unsigned short* hH0 = (unsigned short*)(st);                 // 128 KB
  unsigned short* hH1 = (unsigned short*)(st + (128l << 10));  // 128 KB
  unsigned int* flags = (unsigned int*)(st + (256l << 10));    // 4 KB (1024 flags)
  _Float16* xg = (_Float16*)(ws + (96l << 20));    // 256 MB -> total 352 MB

  cvt_f32_f16<<<256, 256, 0, stream>>>(Wx, Wx16, G_ * I_);
  cvt_f32_f16<<<256, 256, 0, stream>>>(Wh, Whh, G_ * H_);
  zero_counters<<<1, 256, 0, stream>>>(flags, 1024);

  const int nGemmBlk = (S_ * B_ / 128) * (G_ / 128);
  gemm_xg<<<nGemmBlk, 256, 0, stream>>>(x, Wx16, bx, bh, xg);

  lstm_scan<<<256, 256, 0, stream>>>(xg, Whh, hH0, hH1, out, hT, cT, flags);
}

// Round 14
// 2005.845 us; speedup vs baseline: 1.5567x; 1.5567x over previous
//
#include <hip/hip_runtime.h>

#define S_ 512
#define B_ 64
#define I_ 1024
#define H_ 1024
#define G_ 4096   // 4*H
#define ROWB 2080 // LDS row stride bytes: 130*16 -> conflict-free frag reads (verified R6)

typedef _Float16 f16x4 __attribute__((ext_vector_type(4)));
typedef _Float16 f16x8 __attribute__((ext_vector_type(8)));
typedef float f32x4 __attribute__((ext_vector_type(4)));

// ---------------- f32 -> f16 (plain) ----------------
__global__ __launch_bounds__(256) void cvt_f32_f16(const float* __restrict__ src,
                                                   _Float16* __restrict__ dst, int n) {
  const int stride = gridDim.x * blockDim.x * 4;
  for (long i = (long)(blockIdx.x * blockDim.x + threadIdx.x) * 4; i < n; i += stride) {
    const float4 v = *(const float4*)(src + i);
    f16x4 o;
    o.x = (_Float16)v.x;
    o.y = (_Float16)v.y;
    o.z = (_Float16)v.z;
    o.w = (_Float16)v.w;
    *(f16x4*)(dst + i) = o;
  }
}

// ---------------- async global->LDS helper (16B per lane) ----------------
__device__ __forceinline__ void gload16(const void* g, void* l) {
  __builtin_amdgcn_global_load_lds(
      (const __attribute__((address_space(1))) unsigned int*)g,
      (__attribute__((address_space(3))) unsigned int*)l, 16, 0, 0);
}

// ---------------- coherent (bypass L1/L2, served by MALL) access helpers ----------------
__device__ __forceinline__ uint4 ld_coh_x4(const unsigned int* p) {
  uint4 v;
  asm volatile("global_load_dwordx4 %0, %1, off sc0 sc1" : "=v"(v) : "v"(p) : "memory");
  return v;
}
__device__ __forceinline__ unsigned ld_coh_wait(const unsigned int* p) {
  unsigned v;
  asm volatile("global_load_dword %0, %1, off sc0 sc1\n\ts_waitcnt vmcnt(0)"
               : "=v"(v) : "v"(p) : "memory");
  return v;
}
__device__ __forceinline__ void st_coh(unsigned int* p, unsigned int v) {
  asm volatile("global_store_dword %0, %1, off sc0 sc1" : : "v"(p), "v"(v) : "memory");
}
__device__ __forceinline__ void st_coh16(unsigned short* p, unsigned int v) {
  asm volatile("global_store_short %0, %1, off sc0 sc1" : : "v"(p), "v"(v) : "memory");
}
__device__ __forceinline__ void wait_vm0() {
  asm volatile("s_waitcnt vmcnt(0)" ::: "memory");
}
__device__ __forceinline__ f16x8 ld_g_f16x8(const _Float16* p) {
  f16x8 v;
  asm volatile("global_load_dwordx4 %0, %1, off" : "=v"(v) : "v"(p) : "memory");
  return v;
}

// ---------------- x_gates GEMM: C = f16(x) * f16(Wx)^T + (bx+bh), f16 out ----------------
// (verified R10/R11) m97 structure, single product. 128x128 tile, BK=32, 4 waves.
__global__ __launch_bounds__(256) void gemm_xg(const _Float16* __restrict__ A,
                                               const _Float16* __restrict__ Bm,
                                               const float* __restrict__ bx,
                                               const float* __restrict__ bh,
                                               _Float16* __restrict__ C) {
  __shared__ __align__(16) _Float16 As[128 * 32];
  __shared__ __align__(16) _Float16 Bs[128 * 32];
  const int tileN = (blockIdx.x & 31) << 7;
  const int tileM = (blockIdx.x >> 5) << 7;
  const int w = threadIdx.x >> 6;
  const int lane = threadIdx.x & 63;
  const int wm = w & 1, wn = w >> 1;

  const int srow = lane >> 2;
  const int scol = (lane & 3) << 3;
  const long r0 = (long)((2 * w + 0) * 16 + srow);
  const long r1 = (long)((2 * w + 1) * 16 + srow);
  const _Float16* pA0 = A + (tileM + r0) * I_ + scol;
  const _Float16* pA1 = A + (tileM + r1) * I_ + scol;
  const _Float16* pB0 = Bm + (tileN + r0) * I_ + scol;
  const _Float16* pB1 = Bm + (tileN + r1) * I_ + scol;

  f32x4 acc[4][4] = {};
  const int fr = lane & 15;
  const int fk = (lane >> 4) << 3;

  for (int kk = 0; kk < I_; kk += 32) {
    gload16(pA0 + kk, &As[(2 * w + 0) * 512]);
    gload16(pA1 + kk, &As[(2 * w + 1) * 512]);
    gload16(pB0 + kk, &Bs[(2 * w + 0) * 512]);
    gload16(pB1 + kk, &Bs[(2 * w + 1) * 512]);
    __syncthreads();
    f16x8 af[4], bf[4];
#pragma unroll
    for (int i = 0; i < 4; ++i) {
      af[i] = *(const f16x8*)&As[(wm * 64 + i * 16 + fr) * 32 + fk];
      bf[i] = *(const f16x8*)&Bs[(wn * 64 + i * 16 + fr) * 32 + fk];
    }
#pragma unroll
    for (int i = 0; i < 4; ++i)
#pragma unroll
      for (int j = 0; j < 4; ++j)
        acc[i][j] = __builtin_amdgcn_mfma_f32_16x16x32_f16(af[i], bf[j], acc[i][j], 0, 0, 0);
    __syncthreads();
  }

#pragma unroll
  for (int j = 0; j < 4; ++j) {
    const int col = tileN + wn * 64 + j * 16 + fr;
    const float bias = bx[col] + bh[col];
#pragma unroll
    for (int i = 0; i < 4; ++i) {
      const int row0 = tileM + wm * 64 + i * 16 + ((lane >> 4) << 2);
#pragma unroll
      for (int r = 0; r < 4; ++r)
        C[(long)(row0 + r) * G_ + col] = (_Float16)(acc[i][j][r] + bias);
    }
  }
}

// ---------------- flag reset (every launch, stream-ordered) ----------------
__global__ void zero_counters(unsigned int* c, int n) {
  for (int i = threadIdx.x; i < n; i += blockDim.x) c[i] = 0;
}

// ---------------- persistent LSTM scan (R8/R11-verified structure, verbatim) ----------------
// 256 WGs x 256 threads (4 waves), 1 WG/CU. WG=(bg,hs); wave w = gate w.
// Wh pinned in 128 regs/lane (asm loads). h published as ONE f16 plane via
// MALL-coherent stores; reader stages 32KB -> LDS; 32 MFMAs/wave/step.
// Per-WAVE flags; poll wave-split (wave w watches its 16 WGs' 4 flags).
__global__ __launch_bounds__(256, 1) void lstm_scan(
    const _Float16* __restrict__ xg, const _Float16* __restrict__ Whh,
    unsigned short* __restrict__ hH0, unsigned short* __restrict__ hH1,
    float* __restrict__ out, float* __restrict__ hT, float* __restrict__ cT,
    unsigned int* __restrict__ flags) {
  __shared__ __align__(16) char hhS[16 * ROWB];  // 33.3 KB
  __shared__ float gbuf[4][16][16];              // 4 KB
  const int bg = blockIdx.x >> 6;
  const int hs = blockIdx.x & 63;
  const int tid = threadIdx.x;
  const int w = tid >> 6;
  const int lane = tid & 63;
  const int fr = lane & 15;
  const int fkg = lane >> 4;  // 0..3

  // ---- Wh -> regs, once, via asm loads (non-rematerializable) ----
  f16x8 wreg[32];
  {
    const _Float16* wrow = Whh + (long)(w * H_ + hs * 16 + fr) * H_ + fkg * 8;
#pragma unroll
    for (int it = 0; it < 32; ++it) wreg[it] = ld_g_f16x8(wrow + it * 32);
    wait_vm0();
    __builtin_amdgcn_sched_barrier(0);
  }

  const int b = tid >> 4, j = tid & 15;
  const int gb = bg * 16 + b;
  const int gj = hs * 16 + j;
  float c = 0.f;

  // staging source (u32 units): plane f16[64][1024]; this bg's block = 8192 u32
  const unsigned int* sH0 = (const unsigned int*)hH0 + bg * 8192 + tid * 4;
  const unsigned int* sH1 = (const unsigned int*)hH1 + bg * 8192 + tid * 4;
  // LDS dest: chunk ci = i*256+tid -> row = 2i + (tid>>7), col16 = tid&127
  const int lds0 = (tid >> 7) * ROWB + (tid & 127) * 16;
  // fragment read base: row fr, k-group fkg
  const char* hhrow = hhS + fr * ROWB + fkg * 16;
  // poll: wave w watches WGs bg*64 + w*16 + (lane>>2), flag (lane&3)
  const unsigned int* pollp = flags + (bg * 64 + w * 16 + (lane >> 2)) * 4 + (lane & 3);
  unsigned int* myflag = flags + blockIdx.x * 4 + w;

  // xg prefetch for t=0
  float gi = (float)xg[(long)gb * G_ + gj];
  float gf = (float)xg[(long)gb * G_ + gj + H_];
  float gg = (float)xg[(long)gb * G_ + gj + 2 * H_];
  float go = (float)xg[(long)gb * G_ + gj + 3 * H_];

  for (int t = 0; t < S_; ++t) {
    if (t > 0) {
      // ---- wait for h(t-1): all 64 WGs x 4 waves of this batch-group ----
      const unsigned tgt = (unsigned)t;
      while (!__all(ld_coh_wait(pollp) >= tgt)) __builtin_amdgcn_s_sleep(1);
      __syncthreads();

      // ---- stage h(t-1) plane -> LDS (32KB, 8 dwordx4/thread) ----
      const unsigned int* sH = (t & 1) ? sH0 : sH1;
      uint4 qh[8];
#pragma unroll
      for (int i = 0; i < 8; ++i) qh[i] = ld_coh_x4(sH + i * 1024);
      wait_vm0();
      __builtin_amdgcn_sched_barrier(0);
#pragma unroll
      for (int i = 0; i < 8; ++i)
        *(uint4*)(hhS + lds0 + i * (2 * ROWB)) = qh[i];
      __syncthreads();

      // ---- gates = h @ Wh^T ; 4 independent MFMA chains of 8 ----
      f32x4 a0 = {}, a1 = {}, a2 = {}, a3 = {};
#pragma unroll
      for (int it = 0; it < 32; it += 4) {
        a0 = __builtin_amdgcn_mfma_f32_16x16x32_f16(*(const f16x8*)(hhrow + it * 64), wreg[it], a0, 0, 0, 0);
        a1 = __builtin_amdgcn_mfma_f32_16x16x32_f16(*(const f16x8*)(hhrow + (it + 1) * 64), wreg[it + 1], a1, 0, 0, 0);
        a2 = __builtin_amdgcn_mfma_f32_16x16x32_f16(*(const f16x8*)(hhrow + (it + 2) * 64), wreg[it + 2], a2, 0, 0, 0);
        a3 = __builtin_amdgcn_mfma_f32_16x16x32_f16(*(const f16x8*)(hhrow + (it + 3) * 64), wreg[it + 3], a3, 0, 0, 0);
      }
#pragma unroll
      for (int r = 0; r < 4; ++r)
        gbuf[w][fkg * 4 + r][fr] = (a0[r] + a1[r]) + (a2[r] + a3[r]);
      __syncthreads();
      gi += gbuf[0][b][j];
      gf += gbuf[1][b][j];
      gg += gbuf[2][b][j];
      go += gbuf[3][b][j];
    }

    const float iv = 1.f / (1.f + __expf(-gi));
    const float fv = 1.f / (1.f + __expf(-gf));
    const float gv = tanhf(gg);
    const float ov = 1.f / (1.f + __expf(-go));
    c = fv * c + iv * gv;
    const float hn = ov * tanhf(c);

    if (t + 1 < S_) {
      // ---- publish h(t) to parity plane, wave-drain, wave flag ----
      unsigned short* pH = ((t & 1) ? hH1 : hH0) + gb * 1024 + gj;
      st_coh16(pH, (unsigned)__builtin_bit_cast(unsigned short, (_Float16)hn));
      wait_vm0();  // this wave's h store visible at the coherent point
      if (lane == 0) st_coh(myflag, (unsigned)(t + 1));
      // off-critical-path work after the flag
      out[((long)gb * S_ + t) * H_ + gj] = hn;
      const _Float16* xq = xg + ((long)(t + 1) * B_ + gb) * G_ + gj;
      gi = (float)xq[0];
      gf = (float)xq[H_];
      gg = (float)xq[2 * H_];
      go = (float)xq[3 * H_];
    } else {
      out[((long)gb * S_ + t) * H_ + gj] = hn;
      hT[gb * H_ + gj] = hn;
      cT[gb * H_ + gj] = c;
    }
  }
}

// ---------------- launch ----------------
extern "C" void kernel_launch(void* const* d_in, const int* in_sizes, int n_in,
                              void* d_out, int out_size, void* d_ws, size_t ws_size,
                              hipStream_t stream) {
  const float* x = (const float*)d_in[0];
  const float* Wx = (const float*)d_in[1];
  const float* bx = (const float*)d_in[2];
  const float* Wh = (const float*)d_in[3];
  const float* bh = (const float*)d_in[4];

  float* out = (float*)d_out;            // [64][512][1024]
  float* hT = out + (long)B_ * S_ * H_;  // [64][1024]
  float* cT = hT + (long)B_ * H_;        // [64][1024]

  char* ws = (char*)d_ws;
  _Float16* Wx16 = (_Float16*)ws;                  // 8 MB
  _Float16* Whh = (_Float16*)(ws + (8l << 20));    // 8 MB
  _Float16* x16 = (_Float16*)(ws + (16l << 20));   // 64 MB
  char* st = ws + (80l << 20);
  unsigned short* hH0 = (unsigned short*)(st);                 // 128 KB
  unsigned short* hH1 = (unsigned short*)(st + (128l << 10));  // 128 KB
  unsigned int* flags = (unsigned int*)(st + (256l << 10));    // 4 KB (1024 flags)
  _Float16* xg = (_Float16*)(ws + (96l << 20));    // 256 MB -> total 352 MB

  cvt_f32_f16<<<256, 256, 0, stream>>>(Wx, Wx16, G_ * I_);
  cvt_f32_f16<<<256, 256, 0, stream>>>(Wh, Whh, G_ * H_);
  cvt_f32_f16<<<2048, 256, 0, stream>>>(x, x16, S_ * B_ * I_);
  zero_counters<<<1, 256, 0, stream>>>(flags, 1024);

  const int nGemmBlk = (S_ * B_ / 128) * (G_ / 128);
  gemm_xg<<<nGemmBlk, 256, 0, stream>>>(x16, Wx16, bx, bh, xg);

  lstm_scan<<<256, 256, 0, stream>>>(xg, Whh, hH0, hH1, out, hT, cT, flags);
}